// Round 18
// baseline (99.588 us; speedup 1.0000x reference)
//
#include <hip/hip_runtime.h>
#include <hip/hip_fp16.h>
#include <cstdint>

#define HH 128
#define WW 128
#define NBATCH 2
#define CIN 256
#define COUT 256
#define DGN 4
#define K2 9
#define HW (HH*WW)
#define KTOT (K2*CIN)          // 2304, K index = dg*576 + tap*64 + c (dg-major)
#define NKS (KTOT/16)          // 144 k16-slices
#define NMT32 (COUT/32)        // 8 m-tiles of 32
#define NKP 36                 // k-pairs (64 ch each) = dg*9 + tap
#define WROWS 5
#define WCOLS 68
#define WPX (WROWS*WCOLS)      // 340 pixels; window stored [chunk][px] col-major

typedef __attribute__((ext_vector_type(8))) short short8;
typedef __attribute__((ext_vector_type(8))) _Float16 f16x8;
typedef __attribute__((ext_vector_type(16))) float f32x16;

struct __align__(16) H2x4 { __half2 h[4]; };

#define LGKM0() asm volatile("s_waitcnt lgkmcnt(0)" ::: "memory")
#define RAWBAR() do { LGKM0(); __builtin_amdgcn_s_barrier(); } while (0)

static __device__ __forceinline__ unsigned short f2h_u(float f) {
    _Float16 h = (_Float16)f;
    return __builtin_bit_cast(unsigned short, h);
}

// ---- prologue 1: NCHW fp32 -> NHWC fp16 (xT[n][p][c], 512B per pixel) ----
__global__ __launch_bounds__(256) void tr_kernel(const float* __restrict__ x,
                                                 unsigned short* __restrict__ xT) {
    __shared__ float tile[64][65];
    const int b  = blockIdx.x;
    const int pt = b & 255;
    const int ct = (b >> 8) & 3;
    const int n  = b >> 10;
    const int p0 = pt * 64, c0 = ct * 64;
    const float* xn = x + (size_t)n * CIN * HW;
    const int tid = threadIdx.x;
    {
        const int tx = tid & 63, ty = tid >> 6;
        #pragma unroll
        for (int i = 0; i < 16; ++i) {
            int ch = i * 4 + ty;
            tile[ch][tx] = xn[(size_t)(c0 + ch) * HW + p0 + tx];
        }
    }
    __syncthreads();
    char* xb = (char*)xT + (size_t)n * HW * 512;
    {
        const int cx = tid & 31, pq = tid >> 5;
        #pragma unroll
        for (int i = 0; i < 8; ++i) {
            int p = i * 8 + pq;
            unsigned lo = f2h_u(tile[2 * cx][p]);
            unsigned hi = f2h_u(tile[2 * cx + 1][p]);
            *(unsigned*)(xb + (size_t)(p0 + p) * 512 + c0 * 2 + cx * 4) = lo | (hi << 16);
        }
    }
}

// ---- prologue 2: weights -> 32x32x16 A-fragments, dg-major K ordering ----
__global__ void wa_kernel(const float* __restrict__ w, unsigned int* __restrict__ wA) {
    int t = blockIdx.x * blockDim.x + threadIdx.x;
    if (t >= NKS * NMT32 * 64 * 4) return;
    int r  = t & 3;
    int l  = (t >> 2) & 63;
    int mt = (t >> 8) & 7;
    int ks = t >> 11;
    int m  = mt * 32 + (l & 31);
    int k0 = ks * 16 + (l >> 5) * 8 + r * 2;
    unsigned int pk = 0;
    #pragma unroll
    for (int e = 0; e < 2; ++e) {
        int k = k0 + e;                 // dg-major index
        int dg  = k / 576;
        int rem = k - dg * 576;
        int tap = rem >> 6;
        int c   = dg * 64 + (rem & 63);
        float v = w[(size_t)m * (CIN * K2) + c * 9 + tap];
        pk |= ((unsigned int)f2h_u(v)) << (16 * e);
    }
    wA[t] = pk;
}

// ---- main: 8 waves, 64 px, M=256; col-major window; own-pxh consumers ----
__global__ __launch_bounds__(512, 4) void deform_mfma_kernel(
    const unsigned short* __restrict__ xT,
    const float* __restrict__ shape,
    const float* __restrict__ wo,
    const short8* __restrict__ wAf,
    float* __restrict__ out)
{
    __shared__ __align__(16) char smem[78336];
    float*  s_pp  = (float*)smem;                      // [36][64][2]  18432 B
    char*   s_stg = smem + 18432;                      // [8 chunk][340 px][16B] 43520 B
    short8* bufB  = (short8*)(smem + 18432 + 43520);   // [2][8][64]   16384 B

    const int tid = threadIdx.x;
    const int bid = blockIdx.x;                    // 512 blocks
    const int tile = (bid & 7) * 64 + (bid >> 3);  // XCD-chunked swizzle
    const int wh = tile & 1;
    const int h  = (tile >> 1) & 127;
    const int n  = tile >> 8;
    const int w0 = wh * 64;
    const int ybase = h - 2, xbase = w0 - 2;

    // ---- coord phase: 36 (dg,tap) x 64 px -> (py,px) ----
    for (int s = tid; s < DGN * K2 * 64; s += 512) {
        int p64 = s & 63;
        int dgk = s >> 6;
        int tap = dgk % 9;
        int w   = w0 + p64;
        float s0 = shape[((size_t)(n * 2 + 0)) * HW + h * WW + w];
        float s1 = shape[((size_t)(n * 2 + 1)) * HW + h * WW + w];
        float dy = wo[dgk * 4 + 0] * s0 + wo[dgk * 4 + 1] * s1;
        float dx = wo[dgk * 4 + 2] * s0 + wo[dgk * 4 + 3] * s1;
        s_pp[(dgk * 64 + p64) * 2 + 0] = (float)(h + (tap / 3) - 1) + dy;
        s_pp[(dgk * 64 + p64) * 2 + 1] = (float)(w + (tap % 3) - 1) + dx;
    }
    __syncthreads();

    const int wave = tid >> 6;
    const int lane = tid & 63;
    // builder role: px-half pxh, k16-slice ksl (unchanged from R17)
    const int pxh  = wave & 1;
    const int ksl  = wave >> 1;              // 0..3
    const int bpx  = pxh * 32 + (lane & 31); // build pixel (block-local)
    const int koct = lane >> 5;              // channel octet within slice
    const int chnk = 2 * ksl + koct;         // 16B chunk within 128B dg-row
    // consumer role: own px-half cpxh, m-tile pair {2*cmg, 2*cmg+1}
    const int cpxh = wave & 1;
    const int cmg  = wave >> 1;              // 0..3

    const char* xb = (const char*)xT + (size_t)n * HW * 512;

    f32x16 acc0, acc1;                       // m-tiles 2*cmg, 2*cmg+1 (pixels cpxh-half)
    #pragma unroll
    for (int r = 0; r < 16; ++r) { acc0[r] = 0.f; acc1[r] = 0.f; }

    // ---- stage dg window: thread p owns pixel p; writes contiguous per chunk ----
    auto stageDG = [&](int dg) {
        const char* xsrc = xb + dg * 128;
        for (int p = tid; p < WPX; p += 512) {
            int sy = (unsigned)p / WCOLS;
            int sx = p - sy * WCOLS;
            int r = min(max(ybase + sy, 0), HH - 1);
            int c = min(max(xbase + sx, 0), WW - 1);
            const char* src = xsrc + (size_t)(r * WW + c) * 512;
            uint4 v[8];
            #pragma unroll
            for (int c8 = 0; c8 < 8; ++c8)
                v[c8] = *(const uint4*)(src + c8 * 16);
            #pragma unroll
            for (int c8 = 0; c8 < 8; ++c8)
                *(uint4*)(s_stg + (c8 * WPX + p) * 16) = v[c8];
        }
    };

    // ---- build one k-pair's B fragment from the LDS window (global fallback) ----
    auto buildKP = [&](int dg, int tap, int slot) {
        int dgk = dg * 9 + tap;
        float py  = s_pp[(dgk * 64 + bpx) * 2 + 0];
        float pxf = s_pp[(dgk * 64 + bpx) * 2 + 1];
        float y0f = floorf(py), x0f = floorf(pxf);
        float ly = py - y0f, lx = pxf - x0f;
        int y0 = (int)y0f, x0 = (int)x0f;
        float wgt[4] = {(1.f - ly) * (1.f - lx), (1.f - ly) * lx,
                        ly * (1.f - lx),         ly * lx};
        short8 v[4]; unsigned short cwh[4];
        const char* cbase = s_stg + chnk * (WPX * 16);
        #pragma unroll
        for (int j = 0; j < 4; ++j) {
            int yi = y0 + (j >> 1);
            int xi = x0 + (j & 1);
            bool valid = (yi >= 0) && (yi < HH) && (xi >= 0) && (xi < WW);
            int yc = min(max(yi, 0), HH - 1);
            int xc = min(max(xi, 0), WW - 1);
            cwh[j] = f2h_u(valid ? wgt[j] : 0.0f);
            int sy = yc - ybase, sx = xc - xbase;
            if ((unsigned)sy < (unsigned)WROWS && (unsigned)sx < (unsigned)WCOLS) {
                int pl = sy * WCOLS + sx;
                v[j] = *(const short8*)(cbase + pl * 16);
            } else {
                v[j] = *(const short8*)(xb + (size_t)(yc * WW + xc) * 512 + dg * 128 + chnk * 16);
            }
        }
        __half2 w0h = __builtin_bit_cast(__half2, (unsigned)(cwh[0] | ((unsigned)cwh[1] << 16)));
        __half2 w2h = __builtin_bit_cast(__half2, (unsigned)(cwh[2] | ((unsigned)cwh[3] << 16)));
        __half2 c0 = __low2half2(w0h), c1 = __high2half2(w0h);
        __half2 c2 = __low2half2(w2h), c3 = __high2half2(w2h);
        H2x4 a0 = __builtin_bit_cast(H2x4, v[0]);
        H2x4 a1 = __builtin_bit_cast(H2x4, v[1]);
        H2x4 a2 = __builtin_bit_cast(H2x4, v[2]);
        H2x4 a3 = __builtin_bit_cast(H2x4, v[3]);
        H2x4 r;
        #pragma unroll
        for (int j = 0; j < 4; ++j) {
            __half2 t = __hmul2(c0, a0.h[j]);
            t = __hfma2(c1, a1.h[j], t);
            t = __hfma2(c2, a2.h[j], t);
            t = __hfma2(c3, a3.h[j], t);
            r.h[j] = t;
        }
        bufB[(slot * 8 + pxh * 4 + ksl) * 64 + lane] = __builtin_bit_cast(short8, r);
    };

    // A fragments for k-pair i: 4 k16-slices x this wave's 2 m-tiles
    auto loadA = [&](int i, short8 A[8]) {
        const short8* wa = wAf + ((size_t)(i * 4) * NMT32 + cmg * 2) * 64 + lane;
        #pragma unroll
        for (int s = 0; s < 4; ++s) {
            A[s * 2 + 0] = wa[(s * NMT32 + 0) * 64];
            A[s * 2 + 1] = wa[(s * NMT32 + 1) * 64];
        }
    };
    // consume: 4 bufB reads (own pxh), each feeds 2 MFMAs (2 m-tiles)
    auto mfmaStep = [&](int slot, const short8 A[8]) {
        __builtin_amdgcn_s_setprio(1);
        #pragma unroll
        for (int s = 0; s < 4; ++s) {
            f16x8 b  = __builtin_bit_cast(f16x8, bufB[(slot * 8 + cpxh * 4 + s) * 64 + lane]);
            f16x8 a0 = __builtin_bit_cast(f16x8, A[s * 2 + 0]);
            f16x8 a1 = __builtin_bit_cast(f16x8, A[s * 2 + 1]);
            acc0 = __builtin_amdgcn_mfma_f32_32x32x16_f16(a0, b, acc0, 0, 0, 0);
            acc1 = __builtin_amdgcn_mfma_f32_32x32x16_f16(a1, b, acc1, 0, 0, 0);
        }
        __builtin_amdgcn_s_setprio(0);
    };

    // ---- main: 4 dg phases x (stage + 9 taps, ping-pong bufB) ----
    short8 A[8];
    for (int dg = 0; dg < DGN; ++dg) {
        stageDG(dg);
        __syncthreads();                 // stage visible to all waves
        buildKP(dg, 0, 0);
        RAWBAR();
        for (int tap = 0; tap < 9; ++tap) {
            loadA(dg * 9 + tap, A);
            if (tap < 8) buildKP(dg, tap + 1, (tap + 1) & 1);
            mfmaStep(tap & 1, A);
            RAWBAR();                    // bufB slot ready for next iter; stage reads done
        }
    }

    // ---- epilogue: direct coalesced stores (32x32 C/D layout) ----
    // col = lane&31 -> pixel cpxh*32 + col; row = (reg&3) + 8*(reg>>2) + 4*(lane>>5)
    const int cl = lane & 31;
    const int rb = 4 * (lane >> 5);
    #pragma unroll
    for (int e = 0; e < 2; ++e) {
        float* on = out + ((size_t)(n * COUT + (cmg * 2 + e) * 32)) * HW
                    + h * WW + w0 + cpxh * 32;
        const f32x16& a = e ? acc1 : acc0;
        #pragma unroll
        for (int reg = 0; reg < 16; ++reg) {
            int m = (reg & 3) + 8 * (reg >> 2) + rb;
            on[(size_t)m * HW + cl] = fmaxf(a[reg], 0.f);
        }
    }
}

extern "C" void kernel_launch(void* const* d_in, const int* in_sizes, int n_in,
                              void* d_out, int out_size, void* d_ws, size_t ws_size,
                              hipStream_t stream) {
    const float* x        = (const float*)d_in[0];
    const float* shape    = (const float*)d_in[1];
    const float* w_offset = (const float*)d_in[2];
    const float* w_adapt  = (const float*)d_in[3];
    float* out = (float*)d_out;

    unsigned int*   wA = (unsigned int*)d_ws;                       // 1.18 MB
    unsigned short* xT = (unsigned short*)((char*)d_ws + 0x130000); // 16.78 MB

    tr_kernel<<<NBATCH * 4 * 256, 256, 0, stream>>>(x, xT);
    int wa_elems = NKS * NMT32 * 64 * 4;
    wa_kernel<<<(wa_elems + 255) / 256, 256, 0, stream>>>(w_adapt, wA);
    deform_mfma_kernel<<<NBATCH * HH * 2, 512, 0, stream>>>(
        xT, shape, w_offset, (const short8*)wA, out);
}

// Round 19
// 84.259 us; speedup vs baseline: 1.1819x; 1.1819x over previous
//
#include <hip/hip_runtime.h>
#include <hip/hip_fp16.h>
#include <cstdint>

#define HH 128
#define WW 128
#define NBATCH 2
#define CIN 256
#define COUT 256
#define DGN 4
#define K2 9
#define HW (HH*WW)
#define KTOT (K2*CIN)          // 2304, K index = dg*576 + tap*64 + c (dg-major)
#define NKS (KTOT/16)          // 144 k16-slices
#define NMT32 (COUT/32)        // 8 m-tiles of 32
#define NKP 36                 // k-pairs (64 ch each) = dg*9 + tap
#define WROWS 5
#define WCOLS 68
#define WPX (WROWS*WCOLS)      // 340 pixels; window stored [chunk][px] col-major

typedef __attribute__((ext_vector_type(8))) short short8;
typedef __attribute__((ext_vector_type(8))) _Float16 f16x8;
typedef __attribute__((ext_vector_type(16))) float f32x16;

struct __align__(16) H2x4 { __half2 h[4]; };

#define LGKM0() asm volatile("s_waitcnt lgkmcnt(0)" ::: "memory")
#define RAWBAR() do { LGKM0(); __builtin_amdgcn_s_barrier(); } while (0)

static __device__ __forceinline__ unsigned short f2h_u(float f) {
    _Float16 h = (_Float16)f;
    return __builtin_bit_cast(unsigned short, h);
}

// ---- prologue 1: NCHW fp32 -> NHWC fp16 (xT[n][p][c], 512B per pixel) ----
__global__ __launch_bounds__(256) void tr_kernel(const float* __restrict__ x,
                                                 unsigned short* __restrict__ xT) {
    __shared__ float tile[64][65];
    const int b  = blockIdx.x;
    const int pt = b & 255;
    const int ct = (b >> 8) & 3;
    const int n  = b >> 10;
    const int p0 = pt * 64, c0 = ct * 64;
    const float* xn = x + (size_t)n * CIN * HW;
    const int tid = threadIdx.x;
    {
        const int tx = tid & 63, ty = tid >> 6;
        #pragma unroll
        for (int i = 0; i < 16; ++i) {
            int ch = i * 4 + ty;
            tile[ch][tx] = xn[(size_t)(c0 + ch) * HW + p0 + tx];
        }
    }
    __syncthreads();
    char* xb = (char*)xT + (size_t)n * HW * 512;
    {
        const int cx = tid & 31, pq = tid >> 5;
        #pragma unroll
        for (int i = 0; i < 8; ++i) {
            int p = i * 8 + pq;
            unsigned lo = f2h_u(tile[2 * cx][p]);
            unsigned hi = f2h_u(tile[2 * cx + 1][p]);
            *(unsigned*)(xb + (size_t)(p0 + p) * 512 + c0 * 2 + cx * 4) = lo | (hi << 16);
        }
    }
}

// ---- prologue 2: weights -> 32x32x16 A-fragments, dg-major K ordering ----
__global__ void wa_kernel(const float* __restrict__ w, unsigned int* __restrict__ wA) {
    int t = blockIdx.x * blockDim.x + threadIdx.x;
    if (t >= NKS * NMT32 * 64 * 4) return;
    int r  = t & 3;
    int l  = (t >> 2) & 63;
    int mt = (t >> 8) & 7;
    int ks = t >> 11;
    int m  = mt * 32 + (l & 31);
    int k0 = ks * 16 + (l >> 5) * 8 + r * 2;
    unsigned int pk = 0;
    #pragma unroll
    for (int e = 0; e < 2; ++e) {
        int k = k0 + e;                 // dg-major index
        int dg  = k / 576;
        int rem = k - dg * 576;
        int tap = rem >> 6;
        int c   = dg * 64 + (rem & 63);
        float v = w[(size_t)m * (CIN * K2) + c * 9 + tap];
        pk |= ((unsigned int)f2h_u(v)) << (16 * e);
    }
    wA[t] = pk;
}

// ---- main: 8 waves, 64 px, M=256; col-major LDS window; LDS gathers ----
__global__ __launch_bounds__(512, 4) void deform_mfma_kernel(
    const unsigned short* __restrict__ xT,
    const float* __restrict__ shape,
    const float* __restrict__ wo,
    const short8* __restrict__ wAf,
    float* __restrict__ out)
{
    __shared__ __align__(16) char smem[78336];
    float*  s_pp  = (float*)smem;                      // [36][64][2]  18432 B
    char*   s_stg = smem + 18432;                      // [8 chunk][340 px][16B] 43520 B
    short8* bufB  = (short8*)(smem + 18432 + 43520);   // [2][8][64]   16384 B

    const int tid = threadIdx.x;
    const int bid = blockIdx.x;                    // 512 blocks
    const int tile = (bid & 7) * 64 + (bid >> 3);  // XCD-chunked swizzle
    const int wh = tile & 1;
    const int h  = (tile >> 1) & 127;
    const int n  = tile >> 8;
    const int w0 = wh * 64;
    const int ybase = h - 2, xbase = w0 - 2;

    // ---- coord phase: 36 (dg,tap) x 64 px -> (py,px) ----
    for (int s = tid; s < DGN * K2 * 64; s += 512) {
        int p64 = s & 63;
        int dgk = s >> 6;
        int tap = dgk % 9;
        int w   = w0 + p64;
        float s0 = shape[((size_t)(n * 2 + 0)) * HW + h * WW + w];
        float s1 = shape[((size_t)(n * 2 + 1)) * HW + h * WW + w];
        float dy = wo[dgk * 4 + 0] * s0 + wo[dgk * 4 + 1] * s1;
        float dx = wo[dgk * 4 + 2] * s0 + wo[dgk * 4 + 3] * s1;
        s_pp[(dgk * 64 + p64) * 2 + 0] = (float)(h + (tap / 3) - 1) + dy;
        s_pp[(dgk * 64 + p64) * 2 + 1] = (float)(w + (tap % 3) - 1) + dx;
    }
    __syncthreads();

    const int wave = tid >> 6;
    const int lane = tid & 63;
    // builder role: px-half pxh, k16-slice ksl
    const int pxh  = wave & 1;
    const int ksl  = wave >> 1;              // 0..3
    const int bpx  = pxh * 32 + (lane & 31); // build pixel (block-local)
    const int koct = lane >> 5;              // channel octet within slice
    const int chnk = 2 * ksl + koct;         // 16B chunk within 128B dg-row
    // consumer role: m-tile32 = wave
    const int mt   = wave;

    const char* xb = (const char*)xT + (size_t)n * HW * 512;

    f32x16 acc0, acc1;
    #pragma unroll
    for (int r = 0; r < 16; ++r) { acc0[r] = 0.f; acc1[r] = 0.f; }

    // ---- stage dg window: [chunk][px] col-major (reads conflict-free) ----
    auto stageDG = [&](int dg) {
        const char* xsrc = xb + dg * 128;
        for (int i = tid; i < WPX * 8; i += 512) {
            int chunk = i & 7;
            int p = i >> 3;
            int sy = (unsigned)p / WCOLS;
            int sx = p - sy * WCOLS;
            int r = min(max(ybase + sy, 0), HH - 1);
            int c = min(max(xbase + sx, 0), WW - 1);
            short8 v = *(const short8*)(xsrc + (size_t)(r * WW + c) * 512 + chunk * 16);
            *(short8*)(s_stg + (chunk * WPX + p) * 16) = v;
        }
    };

    // ---- build one k-pair's B fragment from the LDS window (global fallback) ----
    auto buildKP = [&](int dg, int tap, int slot) {
        int dgk = dg * 9 + tap;
        float py  = s_pp[(dgk * 64 + bpx) * 2 + 0];
        float pxf = s_pp[(dgk * 64 + bpx) * 2 + 1];
        float y0f = floorf(py), x0f = floorf(pxf);
        float ly = py - y0f, lx = pxf - x0f;
        int y0 = (int)y0f, x0 = (int)x0f;
        float wgt[4] = {(1.f - ly) * (1.f - lx), (1.f - ly) * lx,
                        ly * (1.f - lx),         ly * lx};
        short8 v[4]; unsigned short cwh[4];
        const char* cbase = s_stg + chnk * (WPX * 16);
        #pragma unroll
        for (int j = 0; j < 4; ++j) {
            int yi = y0 + (j >> 1);
            int xi = x0 + (j & 1);
            bool valid = (yi >= 0) && (yi < HH) && (xi >= 0) && (xi < WW);
            int yc = min(max(yi, 0), HH - 1);
            int xc = min(max(xi, 0), WW - 1);
            cwh[j] = f2h_u(valid ? wgt[j] : 0.0f);
            int sy = yc - ybase, sx = xc - xbase;
            if ((unsigned)sy < (unsigned)WROWS && (unsigned)sx < (unsigned)WCOLS) {
                int pl = sy * WCOLS + sx;
                v[j] = *(const short8*)(cbase + pl * 16);
            } else {
                v[j] = *(const short8*)(xb + (size_t)(yc * WW + xc) * 512 + dg * 128 + chnk * 16);
            }
        }
        __half2 w0h = __builtin_bit_cast(__half2, (unsigned)(cwh[0] | ((unsigned)cwh[1] << 16)));
        __half2 w2h = __builtin_bit_cast(__half2, (unsigned)(cwh[2] | ((unsigned)cwh[3] << 16)));
        __half2 c0 = __low2half2(w0h), c1 = __high2half2(w0h);
        __half2 c2 = __low2half2(w2h), c3 = __high2half2(w2h);
        H2x4 a0 = __builtin_bit_cast(H2x4, v[0]);
        H2x4 a1 = __builtin_bit_cast(H2x4, v[1]);
        H2x4 a2 = __builtin_bit_cast(H2x4, v[2]);
        H2x4 a3 = __builtin_bit_cast(H2x4, v[3]);
        H2x4 r;
        #pragma unroll
        for (int j = 0; j < 4; ++j) {
            __half2 t = __hmul2(c0, a0.h[j]);
            t = __hfma2(c1, a1.h[j], t);
            t = __hfma2(c2, a2.h[j], t);
            t = __hfma2(c3, a3.h[j], t);
            r.h[j] = t;
        }
        bufB[(slot * 8 + pxh * 4 + ksl) * 64 + lane] = __builtin_bit_cast(short8, r);
    };

    auto loadA = [&](int i, short8 A[4]) {
        const short8* wa = wAf + ((size_t)(i * 4) * NMT32 + mt) * 64 + lane;
        A[0] = wa[0];
        A[1] = wa[NMT32 * 64];
        A[2] = wa[2 * NMT32 * 64];
        A[3] = wa[3 * NMT32 * 64];
    };
    auto mfmaStep = [&](int slot, const short8 A[4]) {
        __builtin_amdgcn_s_setprio(1);
        #pragma unroll
        for (int s = 0; s < 4; ++s) {
            f16x8 a  = __builtin_bit_cast(f16x8, A[s]);
            f16x8 b0 = __builtin_bit_cast(f16x8, bufB[(slot * 8 + s) * 64 + lane]);
            f16x8 b1 = __builtin_bit_cast(f16x8, bufB[(slot * 8 + 4 + s) * 64 + lane]);
            acc0 = __builtin_amdgcn_mfma_f32_32x32x16_f16(a, b0, acc0, 0, 0, 0);
            acc1 = __builtin_amdgcn_mfma_f32_32x32x16_f16(a, b1, acc1, 0, 0, 0);
        }
        __builtin_amdgcn_s_setprio(0);
    };

    // ---- main: 4 dg phases x (stage + 9 taps, ping-pong bufB) ----
    short8 A[4];
    for (int dg = 0; dg < DGN; ++dg) {
        stageDG(dg);
        __syncthreads();                 // stage visible to all waves
        buildKP(dg, 0, 0);
        RAWBAR();
        for (int tap = 0; tap < 9; ++tap) {
            loadA(dg * 9 + tap, A);
            if (tap < 8) buildKP(dg, tap + 1, (tap + 1) & 1);
            mfmaStep(tap & 1, A);
            RAWBAR();                    // bufB slot ready for next iter; stage reads done
        }
    }

    // ---- epilogue: direct coalesced stores (32x32 C/D layout) ----
    // col = lane&31 (pixel), row = (reg&3) + 8*(reg>>2) + 4*(lane>>5)
    const int cl = lane & 31;
    const int rb = 4 * (lane >> 5);
    float* on = out + ((size_t)(n * COUT + mt * 32)) * HW + h * WW + w0;
    #pragma unroll
    for (int reg = 0; reg < 16; ++reg) {
        int m = (reg & 3) + 8 * (reg >> 2) + rb;
        on[(size_t)m * HW + cl]      = fmaxf(acc0[reg], 0.f);
        on[(size_t)m * HW + 32 + cl] = fmaxf(acc1[reg], 0.f);
    }
}

extern "C" void kernel_launch(void* const* d_in, const int* in_sizes, int n_in,
                              void* d_out, int out_size, void* d_ws, size_t ws_size,
                              hipStream_t stream) {
    const float* x        = (const float*)d_in[0];
    const float* shape    = (const float*)d_in[1];
    const float* w_offset = (const float*)d_in[2];
    const float* w_adapt  = (const float*)d_in[3];
    float* out = (float*)d_out;

    unsigned int*   wA = (unsigned int*)d_ws;                       // 1.18 MB
    unsigned short* xT = (unsigned short*)((char*)d_ws + 0x130000); // 16.78 MB

    tr_kernel<<<NBATCH * 4 * 256, 256, 0, stream>>>(x, xT);
    int wa_elems = NKS * NMT32 * 64 * 4;
    wa_kernel<<<(wa_elems + 255) / 256, 256, 0, stream>>>(w_adapt, wA);
    deform_mfma_kernel<<<NBATCH * HH * 2, 512, 0, stream>>>(
        xT, shape, w_offset, (const short8*)wA, out);
}

// Round 20
// 76.940 us; speedup vs baseline: 1.2944x; 1.0951x over previous
//
#include <hip/hip_runtime.h>
#include <hip/hip_fp16.h>
#include <cstdint>

#define HH 128
#define WW 128
#define NBATCH 2
#define CIN 256
#define COUT 256
#define DGN 4
#define K2 9
#define HW (HH*WW)
#define KTOT (K2*CIN)          // 2304, K index = dg*576 + tap*64 + c (dg-major)
#define NKS (KTOT/16)          // 144 k16-slices
#define NMT32 (COUT/32)        // 8 m-tiles of 32
#define NKP 36                 // k-pairs (64 ch each) = dg*9 + tap
#define WROWS 5
#define WCOLS 68
#define WPX (WROWS*WCOLS)      // 340 pixels; window stored [chunk][px] col-major

typedef __attribute__((ext_vector_type(8))) short short8;
typedef __attribute__((ext_vector_type(8))) _Float16 f16x8;
typedef __attribute__((ext_vector_type(16))) float f32x16;

struct __align__(16) H2x4 { __half2 h[4]; };

#define LGKM0() asm volatile("s_waitcnt lgkmcnt(0)" ::: "memory")
#define RAWBAR() do { LGKM0(); __builtin_amdgcn_s_barrier(); } while (0)

static __device__ __forceinline__ unsigned short f2h_u(float f) {
    _Float16 h = (_Float16)f;
    return __builtin_bit_cast(unsigned short, h);
}

// ---- prologue: weights -> 32x32x16 A-fragments, dg-major K ordering ----
__global__ void wa_kernel(const float* __restrict__ w, unsigned int* __restrict__ wA) {
    int t = blockIdx.x * blockDim.x + threadIdx.x;
    if (t >= NKS * NMT32 * 64 * 4) return;
    int r  = t & 3;
    int l  = (t >> 2) & 63;
    int mt = (t >> 8) & 7;
    int ks = t >> 11;
    int m  = mt * 32 + (l & 31);
    int k0 = ks * 16 + (l >> 5) * 8 + r * 2;
    unsigned int pk = 0;
    #pragma unroll
    for (int e = 0; e < 2; ++e) {
        int k = k0 + e;                 // dg-major index
        int dg  = k / 576;
        int rem = k - dg * 576;
        int tap = rem >> 6;
        int c   = dg * 64 + (rem & 63);
        float v = w[(size_t)m * (CIN * K2) + c * 9 + tap];
        pk |= ((unsigned int)f2h_u(v)) << (16 * e);
    }
    wA[t] = pk;
}

// ---- main: 8 waves, 64 px, M=256; col-major LDS window staged直 from NCHW fp32 ----
__global__ __launch_bounds__(512, 4) void deform_mfma_kernel(
    const float* __restrict__ x,
    const float* __restrict__ shape,
    const float* __restrict__ wo,
    const short8* __restrict__ wAf,
    float* __restrict__ out)
{
    __shared__ __align__(16) char smem[78336];
    float*  s_pp  = (float*)smem;                      // [36][64][2]  18432 B
    char*   s_stg = smem + 18432;                      // [8 chunk][340 px][16B] 43520 B
    short8* bufB  = (short8*)(smem + 18432 + 43520);   // [2][8][64]   16384 B

    const int tid = threadIdx.x;
    const int bid = blockIdx.x;                    // 512 blocks
    const int tile = (bid & 7) * 64 + (bid >> 3);  // XCD-chunked swizzle
    const int wh = tile & 1;
    const int h  = (tile >> 1) & 127;
    const int n  = tile >> 8;
    const int w0 = wh * 64;
    const int ybase = h - 2, xbase = w0 - 2;

    // ---- coord phase: 36 (dg,tap) x 64 px -> (py,px) ----
    for (int s = tid; s < DGN * K2 * 64; s += 512) {
        int p64 = s & 63;
        int dgk = s >> 6;
        int tap = dgk % 9;
        int w   = w0 + p64;
        float s0 = shape[((size_t)(n * 2 + 0)) * HW + h * WW + w];
        float s1 = shape[((size_t)(n * 2 + 1)) * HW + h * WW + w];
        float dy = wo[dgk * 4 + 0] * s0 + wo[dgk * 4 + 1] * s1;
        float dx = wo[dgk * 4 + 2] * s0 + wo[dgk * 4 + 3] * s1;
        s_pp[(dgk * 64 + p64) * 2 + 0] = (float)(h + (tap / 3) - 1) + dy;
        s_pp[(dgk * 64 + p64) * 2 + 1] = (float)(w + (tap % 3) - 1) + dx;
    }
    __syncthreads();

    const int wave = tid >> 6;
    const int lane = tid & 63;
    // builder role: px-half pxh, k16-slice ksl
    const int pxh  = wave & 1;
    const int ksl  = wave >> 1;              // 0..3
    const int bpx  = pxh * 32 + (lane & 31); // build pixel (block-local)
    const int koct = lane >> 5;              // channel octet within slice
    const int chnk = 2 * ksl + koct;         // 16B chunk within 128B dg-row
    // consumer role: m-tile32 = wave
    const int mt   = wave;

    const float* xn = x + (size_t)n * CIN * HW;

    f32x16 acc0, acc1;
    #pragma unroll
    for (int r = 0; r < 16; ++r) { acc0[r] = 0.f; acc1[r] = 0.f; }

    // ---- stage dg window from NCHW fp32: thread p owns pixel p ----
    auto stageDG = [&](int dg) {
        const float* xsrc = xn + (size_t)(dg * 64) * HW;
        for (int p = tid; p < WPX; p += 512) {
            int sy = (unsigned)p / WCOLS;
            int sx = p - sy * WCOLS;
            int r = min(max(ybase + sy, 0), HH - 1);
            int c = min(max(xbase + sx, 0), WW - 1);
            const float* src = xsrc + r * WW + c;
            #pragma unroll
            for (int c8 = 0; c8 < 8; ++c8) {
                unsigned d[4];
                #pragma unroll
                for (int j = 0; j < 4; ++j) {
                    float lo = src[(size_t)(c8 * 8 + 2 * j    ) * HW];
                    float hi = src[(size_t)(c8 * 8 + 2 * j + 1) * HW];
                    d[j] = (unsigned)f2h_u(lo) | ((unsigned)f2h_u(hi) << 16);
                }
                *(uint4*)(s_stg + (c8 * WPX + p) * 16) = (uint4){d[0], d[1], d[2], d[3]};
            }
        }
    };

    // ---- build one k-pair's B fragment from the LDS window (global fallback) ----
    auto buildKP = [&](int dg, int tap, int slot) {
        int dgk = dg * 9 + tap;
        float py  = s_pp[(dgk * 64 + bpx) * 2 + 0];
        float pxf = s_pp[(dgk * 64 + bpx) * 2 + 1];
        float y0f = floorf(py), x0f = floorf(pxf);
        float ly = py - y0f, lx = pxf - x0f;
        int y0 = (int)y0f, x0 = (int)x0f;
        float wgt[4] = {(1.f - ly) * (1.f - lx), (1.f - ly) * lx,
                        ly * (1.f - lx),         ly * lx};
        short8 v[4]; unsigned short cwh[4];
        const char* cbase = s_stg + chnk * (WPX * 16);
        #pragma unroll
        for (int j = 0; j < 4; ++j) {
            int yi = y0 + (j >> 1);
            int xi = x0 + (j & 1);
            bool valid = (yi >= 0) && (yi < HH) && (xi >= 0) && (xi < WW);
            int yc = min(max(yi, 0), HH - 1);
            int xc = min(max(xi, 0), WW - 1);
            cwh[j] = f2h_u(valid ? wgt[j] : 0.0f);
            int sy = yc - ybase, sx = xc - xbase;
            if ((unsigned)sy < (unsigned)WROWS && (unsigned)sx < (unsigned)WCOLS) {
                int pl = sy * WCOLS + sx;
                v[j] = *(const short8*)(cbase + pl * 16);
            } else {
                const float* gsrc = xn + (size_t)(dg * 64 + chnk * 8) * HW + yc * WW + xc;
                unsigned d[4];
                #pragma unroll
                for (int q = 0; q < 4; ++q) {
                    float lo = gsrc[(size_t)(2 * q) * HW];
                    float hi = gsrc[(size_t)(2 * q + 1) * HW];
                    d[q] = (unsigned)f2h_u(lo) | ((unsigned)f2h_u(hi) << 16);
                }
                v[j] = __builtin_bit_cast(short8, (uint4){d[0], d[1], d[2], d[3]});
            }
        }
        __half2 w0h = __builtin_bit_cast(__half2, (unsigned)(cwh[0] | ((unsigned)cwh[1] << 16)));
        __half2 w2h = __builtin_bit_cast(__half2, (unsigned)(cwh[2] | ((unsigned)cwh[3] << 16)));
        __half2 c0 = __low2half2(w0h), c1 = __high2half2(w0h);
        __half2 c2 = __low2half2(w2h), c3 = __high2half2(w2h);
        H2x4 a0 = __builtin_bit_cast(H2x4, v[0]);
        H2x4 a1 = __builtin_bit_cast(H2x4, v[1]);
        H2x4 a2 = __builtin_bit_cast(H2x4, v[2]);
        H2x4 a3 = __builtin_bit_cast(H2x4, v[3]);
        H2x4 r;
        #pragma unroll
        for (int j = 0; j < 4; ++j) {
            __half2 t = __hmul2(c0, a0.h[j]);
            t = __hfma2(c1, a1.h[j], t);
            t = __hfma2(c2, a2.h[j], t);
            t = __hfma2(c3, a3.h[j], t);
            r.h[j] = t;
        }
        bufB[(slot * 8 + pxh * 4 + ksl) * 64 + lane] = __builtin_bit_cast(short8, r);
    };

    auto loadA = [&](int i, short8 A[4]) {
        const short8* wa = wAf + ((size_t)(i * 4) * NMT32 + mt) * 64 + lane;
        A[0] = wa[0];
        A[1] = wa[NMT32 * 64];
        A[2] = wa[2 * NMT32 * 64];
        A[3] = wa[3 * NMT32 * 64];
    };
    auto mfmaStep = [&](int slot, const short8 A[4]) {
        __builtin_amdgcn_s_setprio(1);
        #pragma unroll
        for (int s = 0; s < 4; ++s) {
            f16x8 a  = __builtin_bit_cast(f16x8, A[s]);
            f16x8 b0 = __builtin_bit_cast(f16x8, bufB[(slot * 8 + s) * 64 + lane]);
            f16x8 b1 = __builtin_bit_cast(f16x8, bufB[(slot * 8 + 4 + s) * 64 + lane]);
            acc0 = __builtin_amdgcn_mfma_f32_32x32x16_f16(a, b0, acc0, 0, 0, 0);
            acc1 = __builtin_amdgcn_mfma_f32_32x32x16_f16(a, b1, acc1, 0, 0, 0);
        }
        __builtin_amdgcn_s_setprio(0);
    };

    // ---- main: 4 dg phases x (stage + 9 taps, ping-pong bufB) ----
    short8 A[4];
    for (int dg = 0; dg < DGN; ++dg) {
        stageDG(dg);
        __syncthreads();                 // stage visible to all waves
        buildKP(dg, 0, 0);
        RAWBAR();
        for (int tap = 0; tap < 9; ++tap) {
            loadA(dg * 9 + tap, A);
            if (tap < 8) buildKP(dg, tap + 1, (tap + 1) & 1);
            mfmaStep(tap & 1, A);
            RAWBAR();                    // bufB slot ready for next iter; stage reads done
        }
    }

    // ---- epilogue: direct coalesced stores (32x32 C/D layout) ----
    // col = lane&31 (pixel), row = (reg&3) + 8*(reg>>2) + 4*(lane>>5)
    const int cl = lane & 31;
    const int rb = 4 * (lane >> 5);
    float* on = out + ((size_t)(n * COUT + mt * 32)) * HW + h * WW + w0;
    #pragma unroll
    for (int reg = 0; reg < 16; ++reg) {
        int m = (reg & 3) + 8 * (reg >> 2) + rb;
        on[(size_t)m * HW + cl]      = fmaxf(acc0[reg], 0.f);
        on[(size_t)m * HW + 32 + cl] = fmaxf(acc1[reg], 0.f);
    }
}

extern "C" void kernel_launch(void* const* d_in, const int* in_sizes, int n_in,
                              void* d_out, int out_size, void* d_ws, size_t ws_size,
                              hipStream_t stream) {
    const float* x        = (const float*)d_in[0];
    const float* shape    = (const float*)d_in[1];
    const float* w_offset = (const float*)d_in[2];
    const float* w_adapt  = (const float*)d_in[3];
    float* out = (float*)d_out;

    unsigned int* wA = (unsigned int*)d_ws;   // 1.18 MB (only workspace user now)

    int wa_elems = NKS * NMT32 * 64 * 4;
    wa_kernel<<<(wa_elems + 255) / 256, 256, 0, stream>>>(w_adapt, wA);
    deform_mfma_kernel<<<NBATCH * HH * 2, 512, 0, stream>>>(
        x, shape, w_offset, (const short8*)wA, out);
}